// Round 9
// baseline (607.304 us; speedup 1.0000x reference)
//
#include <hip/hip_runtime.h>
#include <hip/hip_bf16.h>

// Problem constants (RelateModel_652835029255)
#define NN 100000
#define EE 600000
#define DD 128
#define GG 256
#define CCL 16

typedef __attribute__((ext_vector_type(8))) short short8;
typedef __attribute__((ext_vector_type(4))) float f32x4;
typedef const __attribute__((address_space(1))) void* gas_t;
typedef __attribute__((address_space(3))) void* las_t;

__device__ __forceinline__ void async_ld16(const void* g, void* l) {
    __builtin_amdgcn_global_load_lds((gas_t)g, (las_t)l, 16, 0, 0);
}
__device__ __forceinline__ unsigned short f2bf(float x) {
    unsigned u = __float_as_uint(x);
    unsigned r = (u + 0x7FFFu + ((u >> 16) & 1u)) >> 16;
    return (unsigned short)r;
}
__device__ __forceinline__ float bf2f(unsigned short b) {
    return __uint_as_float(((unsigned)b) << 16);
}
__device__ __forceinline__ void unpack8(uint4 v, float* f) {
    f[0] = __uint_as_float(v.x << 16); f[1] = __uint_as_float(v.x & 0xFFFF0000u);
    f[2] = __uint_as_float(v.y << 16); f[3] = __uint_as_float(v.y & 0xFFFF0000u);
    f[4] = __uint_as_float(v.z << 16); f[5] = __uint_as_float(v.z & 0xFFFF0000u);
    f[6] = __uint_as_float(v.w << 16); f[7] = __uint_as_float(v.w & 0xFFFF0000u);
}

// ---------------- dtype sniff (f32 vs bf16 tensors) ----------------
__global__ __launch_bounds__(256) void sniff_kernel(const void* __restrict__ xraw, int* __restrict__ flag) {
    int t = threadIdx.x;
    const unsigned short* u = (const unsigned short*)xraw;
    int good = 0;
    #pragma unroll
    for (int i = 0; i < 4; i++) {
        unsigned short b = u[t * 4 + i];
        int e = (b >> 7) & 0xFF;
        if (e >= 107 && e <= 130) good++;
    }
    __shared__ int sg[256];
    sg[t] = good;
    __syncthreads();
    for (int s = 128; s > 0; s >>= 1) { if (t < s) sg[t] += sg[t + s]; __syncthreads(); }
    if (t == 0) flag[0] = (sg[0] >= 900) ? 1 : 0;   // 1 = data is bf16
}

__device__ __forceinline__ float loadf(const void* p, size_t i, int isbf) {
    if (isbf) return bf2f(((const unsigned short*)p)[i]);
    return ((const float*)p)[i];
}

__global__ __launch_bounds__(256) void convx_kernel(const void* __restrict__ xraw, const int* __restrict__ flag,
                                                    __hip_bfloat16* __restrict__ xc) {
    int isbf = flag[0];
    size_t i0 = ((size_t)blockIdx.x * 256 + threadIdx.x) * 8;
    if (i0 >= (size_t)NN * DD) return;
    if (isbf) {
        *(uint4*)(xc + i0) = *(const uint4*)((const __hip_bfloat16*)xraw + i0);
    } else {
        const float* xf = (const float*)xraw;
        unsigned short o[8];
        #pragma unroll
        for (int j = 0; j < 8; j++) o[j] = f2bf(xf[i0 + j]);
        *(uint4*)(xc + i0) = *(uint4*)o;
    }
}

// weights -> per-layer wtL[n][k] (transposed, bf16), k = g*128 + kk (g0=root, g1..4=rel)
__global__ __launch_bounds__(256) void convw_kernel(const void* __restrict__ rel_raw, const void* __restrict__ root_raw,
                                                    const int* __restrict__ flag, __hip_bfloat16* __restrict__ wt) {
    int isbf = flag[0];
    int mat = blockIdx.x;
    int layer = mat / 5, g = mat % 5;
    size_t srcoff = (g == 0) ? (size_t)layer * 16384 : (size_t)(layer * 4 + (g - 1)) * 16384;
    const void* sraw = (g == 0) ? root_raw : rel_raw;
    __hip_bfloat16* dstp = wt + (size_t)layer * 81920 + g * 128;
    for (int idx = threadIdx.x; idx < 16384; idx += 256) {
        int kk = idx >> 7, n = idx & 127;
        float v = loadf(sraw, srcoff + (size_t)kk * 128 + n, isbf);
        dstp[(size_t)n * 640 + kk] = __float2bfloat16(v);
    }
}

// small params -> one f32 block; blocks 9,10 precompute BN gm/ga per layer.
__global__ __launch_bounds__(256) void convp_kernel(const void* bias, const void* bng, const void* bnb,
                                                    const void* bnm, const void* bnv, const void* w1,
                                                    const void* b1, const void* w2, const void* b2,
                                                    const int* __restrict__ flag, float* __restrict__ pf) {
    int isbf = flag[0];
    int b = blockIdx.x, t = threadIdx.x;
    if (b < 9) {
        const void* srcs[9] = {bias, bng, bnb, bnm, bnv, w1, b1, w2, b2};
        const int cnts[9] = {384, 256, 256, 256, 256, 8192, 64, 1024, 16};
        const int offs[9] = {0, 384, 640, 896, 1152, 1408, 9600, 9664, 10688};
        const void* s = srcs[b];
        int c = cnts[b], o = offs[b];
        for (int i = t; i < c; i += 256) pf[o + i] = loadf(s, i, isbf);
    } else {
        int bl = b - 9;
        if (t < 128) {
            float iva = rsqrtf(loadf(bnv, bl * 128 + t, isbf) + 1e-5f);
            float gm = loadf(bng, bl * 128 + t, isbf) * iva;
            float ga = loadf(bnb, bl * 128 + t, isbf) - loadf(bnm, bl * 128 + t, isbf) * gm;
            pf[11008 + bl * 256 + t] = gm;
            pf[11008 + bl * 256 + 128 + t] = ga;
        }
    }
}

// ---------------- CSR build: edges sorted by (dst, rel); store src only ----------------
__global__ __launch_bounds__(256) void count4_kernel(const int* __restrict__ dst, const int* __restrict__ et,
                                                     int* __restrict__ cnt4) {
    int e = blockIdx.x * 256 + threadIdx.x;
    if (e < EE) atomicAdd(&cnt4[dst[e] * 4 + et[e]], 1);
}

// per-node start (startn) + per-(node,rel) write pointers (wptr4)
__global__ __launch_bounds__(256) void allocn_kernel(const int* __restrict__ cnt4, int* __restrict__ counter,
                                                     int* __restrict__ startn, int* __restrict__ wptr4) {
    int n = blockIdx.x * 256 + threadIdx.x;
    int lane = threadIdx.x & 63;
    int4 cv = make_int4(0, 0, 0, 0);
    int c = 0;
    if (n < NN) {
        cv = *(const int4*)(cnt4 + n * 4);
        c = cv.x + cv.y + cv.z + cv.w;
    }
    int v = c;
    #pragma unroll
    for (int d = 1; d < 64; d <<= 1) {
        int o = __shfl_up(v, d);
        if (lane >= d) v += o;
    }
    int base = 0;
    if (lane == 63) base = atomicAdd(counter, v);
    base = __shfl(base, 63);
    if (n < NN) {
        int s = base + v - c;
        startn[n] = s;
        wptr4[n * 4 + 0] = s;
        wptr4[n * 4 + 1] = s + cv.x;
        wptr4[n * 4 + 2] = s + cv.x + cv.y;
        wptr4[n * 4 + 3] = s + cv.x + cv.y + cv.z;
    }
}

__global__ __launch_bounds__(256) void fill4_kernel(const int* __restrict__ src, const int* __restrict__ dst,
                                                    const int* __restrict__ et, int* __restrict__ wptr4,
                                                    int* __restrict__ esrc) {
    int e = blockIdx.x * 256 + threadIdx.x;
    if (e < EE) {
        int pos = atomicAdd(&wptr4[dst[e] * 4 + et[e]], 1);
        esrc[pos] = src[e];
    }
}

// ---------------- flayer v2: fully fused RGCN layer, gather-in-register + LDS-B -------------
// hout = epi( [h | mean_0(h)..mean_3(h)] @ WL ), K=640. Block = 128 nodes x 128 cols,
// 512 thr (8 waves x 16 rows). Two sequential 64-col halves share ONE register-built A.
// Lane (quad,r16): node r16, k-sub-slice quad*8. Gather: per rel, 2-wide edge batches x
// 4 k-slices = 8 indep 16B loads in flight/lane, accumulated f32 -> packed bf16 A-frags.
// B: 80KB XOR-swizzled LDS per half (v6-proven). cf epilogue tile separate (B1 stage overlaps).
__global__ __launch_bounds__(512) void flayer_kernel(const __hip_bfloat16* __restrict__ h_in,
                                                     const int* __restrict__ esrc,
                                                     const int* __restrict__ startn,
                                                     const int* __restrict__ cnt4,
                                                     const __hip_bfloat16* __restrict__ wtL,   // [128 n][640 k]
                                                     const float* __restrict__ bias,
                                                     const float* __restrict__ gmp,
                                                     const float* __restrict__ gap,
                                                     const __hip_bfloat16* __restrict__ hres,
                                                     __hip_bfloat16* __restrict__ hout,
                                                     int do_bn) {
    __shared__ __align__(16) short ldsb[40960];    // 80 KB B half-tile
    __shared__ __align__(16) float cf[128 * 66];   // 33.8 KB epilogue tile
    int t = threadIdx.x;
    int wv = t >> 6, lane = t & 63, quad = lane >> 4, r16 = lane & 15;
    int m0 = blockIdx.x * 128;
    int node = m0 + wv * 16 + r16;
    if (node > NN - 1) node = NN - 1;

    // ---- stage B half 0 (async; flies under the gather below) ----
    #pragma unroll
    for (int i = 0; i < 10; i++) {
        int u = i * 512 + t;
        int nl = u / 80;
        int seg = (u - nl * 80) ^ (nl & 7);
        async_ld16(wtL + (size_t)nl * 640 + seg * 8, &ldsb[u * 8]);
    }

    // ---- build A-frags in registers: A[0..3] = h row, A[4+r*4+kc] = rel-r mean ----
    short8 A[20];
    {
        const __hip_bfloat16* hp = h_in + (size_t)node * 128 + quad * 8;
        #pragma unroll
        for (int kc = 0; kc < 4; kc++) A[kc] = *(const short8*)(hp + kc * 32);
    }
    int s = startn[node];
    int4 cvv = *(const int4*)(cnt4 + node * 4);
    int cr[4] = {cvv.x, cvv.y, cvv.z, cvv.w};
    #pragma unroll
    for (int r = 0; r < 4; r++) {
        int c = cr[r];
        float g[4][8];
        #pragma unroll
        for (int kc = 0; kc < 4; kc++)
            #pragma unroll
            for (int j = 0; j < 8; j++) g[kc][j] = 0.f;
        int i = 0;
        for (; i + 2 <= c; i += 2) {
            int e0 = esrc[s + i];
            int e1 = esrc[s + i + 1];
            const __hip_bfloat16* p0 = h_in + (size_t)e0 * 128 + quad * 8;
            const __hip_bfloat16* p1 = h_in + (size_t)e1 * 128 + quad * 8;
            uint4 v0[4], v1[4];
            #pragma unroll
            for (int kc = 0; kc < 4; kc++) v0[kc] = *(const uint4*)(p0 + kc * 32);
            #pragma unroll
            for (int kc = 0; kc < 4; kc++) v1[kc] = *(const uint4*)(p1 + kc * 32);
            #pragma unroll
            for (int kc = 0; kc < 4; kc++) {
                float f[8];
                unpack8(v0[kc], f);
                #pragma unroll
                for (int j = 0; j < 8; j++) g[kc][j] += f[j];
                unpack8(v1[kc], f);
                #pragma unroll
                for (int j = 0; j < 8; j++) g[kc][j] += f[j];
            }
        }
        if (i < c) {
            int e0 = esrc[s + i];
            const __hip_bfloat16* p0 = h_in + (size_t)e0 * 128 + quad * 8;
            #pragma unroll
            for (int kc = 0; kc < 4; kc++) {
                uint4 v = *(const uint4*)(p0 + kc * 32);
                float f[8];
                unpack8(v, f);
                #pragma unroll
                for (int j = 0; j < 8; j++) g[kc][j] += f[j];
            }
        }
        float w = (c > 0) ? (1.f / (float)c) : 0.f;
        #pragma unroll
        for (int kc = 0; kc < 4; kc++) {
            short8 tmp;
            #pragma unroll
            for (int j = 0; j < 8; j++) tmp[j] = (short)f2bf(g[kc][j] * w);
            A[4 + r * 4 + kc] = tmp;
        }
        s += c;
    }

    f32x4 acc[4];
    #pragma unroll
    for (int half = 0; half < 2; half++) {
        __syncthreads();   // B half staged (vmcnt drained; gathers also complete on half 0)
        #pragma unroll
        for (int nt = 0; nt < 4; nt++) acc[nt] = (f32x4){0.f, 0.f, 0.f, 0.f};
        #pragma unroll
        for (int j = 0; j < 20; j++) {
            #pragma unroll
            for (int nt = 0; nt < 4; nt++) {
                int nl = nt * 16 + r16;
                int unit = nl * 80 + ((j * 4 + quad) ^ (nl & 7));
                short8 b = *(const short8*)&ldsb[unit * 8];
                acc[nt] = __builtin_amdgcn_mfma_f32_16x16x32_bf16(A[j], b, acc[nt], 0, 0, 0);
            }
        }
        __syncthreads();   // all B reads done
        if (half == 0) {
            // stage B half 1 into the same buffer; flies under epilogue-half-0
            #pragma unroll
            for (int i = 0; i < 10; i++) {
                int u = i * 512 + t;
                int nl = u / 80;
                int seg = (u - nl * 80) ^ (nl & 7);
                async_ld16(wtL + (size_t)(64 + nl) * 640 + seg * 8, &ldsb[u * 8]);
            }
        }
        // ---- epilogue for this half: f32 C tile through cf, coalesced bf16x8 stores ----
        #pragma unroll
        for (int nt = 0; nt < 4; nt++) {
            int col = nt * 16 + r16;
            #pragma unroll
            for (int reg = 0; reg < 4; reg++)
                cf[(wv * 16 + quad * 4 + reg) * 66 + col] = acc[nt][reg];
        }
        __syncthreads();   // cf complete
        #pragma unroll
        for (int it = 0; it < 2; it++) {
            int u4 = it * 512 + t;          // 1024 = 128 rows x 8 col-octets
            int row = u4 >> 3, oct = u4 & 7;
            int onode = m0 + row;
            if (onode < NN) {
                int gc = half * 64 + oct * 8;
                const float* cp = cf + row * 66 + oct * 8;
                float a8[8];
                #pragma unroll
                for (int j = 0; j < 8; j++) a8[j] = cp[j] + bias[gc + j];
                if (hres) {
                    float rf[8];
                    unpack8(*(const uint4*)(hres + (size_t)onode * 128 + gc), rf);
                    #pragma unroll
                    for (int j = 0; j < 8; j++) a8[j] += rf[j];
                }
                if (do_bn) {
                    #pragma unroll
                    for (int j = 0; j < 8; j++) {
                        float z = a8[j] * gmp[gc + j] + gap[gc + j];
                        a8[j] = z > 0.f ? z : expm1f(z);
                    }
                }
                unsigned short u[8];
                #pragma unroll
                for (int j = 0; j < 8; j++) u[j] = f2bf(a8[j]);
                *(uint4*)(hout + (size_t)onode * 128 + gc) = *(uint4*)u;
            }
        }
        // loop barrier (top of half 1) guarantees cf reads done & B1 landed
    }
}

// ---------------- global mean pool (batch sorted) ----------------
__global__ __launch_bounds__(256) void pool_kernel(const __hip_bfloat16* __restrict__ h3,
                                                   const int* __restrict__ batch,
                                                   float* __restrict__ pooled) {
    int g = blockIdx.x, t = threadIdx.x;
    int rowpar = t >> 4, colg = t & 15;
    int lo = 0, hi = NN;
    while (lo < hi) { int mid = (lo + hi) >> 1; if (batch[mid] < g) lo = mid + 1; else hi = mid; }
    int s0 = lo;
    hi = NN;
    while (lo < hi) { int mid = (lo + hi) >> 1; if (batch[mid] < g + 1) lo = mid + 1; else hi = mid; }
    int s1 = lo;
    float a[8];
    #pragma unroll
    for (int j = 0; j < 8; j++) a[j] = 0.f;
    for (int n = s0 + rowpar; n < s1; n += 16) {
        float f[8];
        unpack8(*(const uint4*)(h3 + (size_t)n * 128 + colg * 8), f);
        #pragma unroll
        for (int j = 0; j < 8; j++) a[j] += f[j];
    }
    __shared__ float sd[16][128];
    #pragma unroll
    for (int j = 0; j < 8; j++) sd[rowpar][colg * 8 + j] = a[j];
    __syncthreads();
    if (t < 128) {
        float sum = 0.f;
        #pragma unroll
        for (int i = 0; i < 16; i++) sum += sd[i][t];
        int cgn = s1 - s0;
        pooled[g * 128 + t] = sum / (float)(cgn > 0 ? cgn : 1);
    }
}

// ---------------- classifier + log_softmax ----------------
__global__ __launch_bounds__(64) void cls_kernel(const float* __restrict__ pooled,
                                                 const float* __restrict__ pf,
                                                 const int* __restrict__ flag,
                                                 void* __restrict__ out) {
    int g = blockIdx.x, j = threadIdx.x;
    const float* w1 = pf + 1408;
    const float* b1 = pf + 9600;
    const float* w2 = pf + 9664;
    const float* b2 = pf + 10688;
    __shared__ float z[64];
    __shared__ float lg[16];
    const float* p = pooled + g * 128;
    float acc = b1[j];
    for (int d = 0; d < 128; d++) acc += p[d] * w1[d * 64 + j];
    acc = acc > 0.f ? acc : expm1f(acc);
    z[j] = acc;
    __syncthreads();
    if (j < CCL) {
        float l = b2[j];
        for (int k = 0; k < 64; k++) l += z[k] * w2[k * 16 + j];
        lg[j] = l;
    }
    __syncthreads();
    if (j < CCL) {
        float m = lg[0];
        for (int k = 1; k < CCL; k++) m = fmaxf(m, lg[k]);
        float s = 0.f;
        for (int k = 0; k < CCL; k++) s += expf(lg[k] - m);
        float val = lg[j] - m - logf(s);
        if (flag[0]) ((__hip_bfloat16*)out)[g * CCL + j] = __float2bfloat16(val);
        else         ((float*)out)[g * CCL + j] = val;
    }
}

extern "C" void kernel_launch(void* const* d_in, const int* in_sizes, int n_in,
                              void* d_out, int out_size, void* d_ws, size_t ws_size,
                              hipStream_t stream) {
    const void* x_raw    = d_in[0];
    const int* ei        = (const int*)d_in[1];
    const int* et        = (const int*)d_in[2];
    const int* batch     = (const int*)d_in[3];
    const void* rel_raw  = d_in[4];
    const void* root_raw = d_in[5];
    const int* srcp = ei;
    const int* dstp = ei + EE;

    char* ws = (char*)d_ws;
    size_t off = 0;
    auto take = [&](size_t bytes) { size_t r = off; off += (bytes + 1023) & ~(size_t)1023; return r; };
    __hip_bfloat16* xc    = (__hip_bfloat16*)(ws + take((size_t)NN * 128 * 2));
    __hip_bfloat16* hA    = (__hip_bfloat16*)(ws + take((size_t)NN * 128 * 2));
    __hip_bfloat16* hB    = (__hip_bfloat16*)(ws + take((size_t)NN * 128 * 2));
    __hip_bfloat16* hC    = (__hip_bfloat16*)(ws + take((size_t)NN * 128 * 2));
    __hip_bfloat16* wt    = (__hip_bfloat16*)(ws + take((size_t)3 * 81920 * 2));
    float* pf             = (float*)(ws + take((size_t)11520 * 4));
    float* pooled         = (float*)(ws + take((size_t)GG * 128 * 4));
    int* cnt4             = (int*)(ws + take((size_t)NN * 16 + 8));
    int* counter          = cnt4 + NN * 4;
    int* flag             = cnt4 + NN * 4 + 1;
    int* startn           = (int*)(ws + take((size_t)NN * 4));
    int* wptr4            = (int*)(ws + take((size_t)NN * 16));
    int* esrc             = (int*)(ws + take((size_t)EE * 4));

    hipMemsetAsync(cnt4, 0, (size_t)NN * 16 + 4, stream);
    sniff_kernel<<<1, 256, 0, stream>>>(x_raw, flag);
    convx_kernel<<<(NN * DD / 8 + 255) / 256, 256, 0, stream>>>(x_raw, flag, xc);
    convw_kernel<<<15, 256, 0, stream>>>(rel_raw, root_raw, flag, wt);
    convp_kernel<<<11, 256, 0, stream>>>(d_in[6], d_in[7], d_in[8], d_in[9], d_in[10],
                                         d_in[11], d_in[12], d_in[13], d_in[14], flag, pf);
    count4_kernel<<<(EE + 255) / 256, 256, 0, stream>>>(dstp, et, cnt4);
    allocn_kernel<<<(NN + 255) / 256, 256, 0, stream>>>(cnt4, counter, startn, wptr4);
    fill4_kernel<<<(EE + 255) / 256, 256, 0, stream>>>(srcp, dstp, et, wptr4, esrc);

    const __hip_bfloat16* hin = xc;
    __hip_bfloat16* houts[3] = {hA, hB, hC};
    for (int l = 0; l < 3; l++) {
        int bl = l < 2 ? l : 1;
        flayer_kernel<<<(NN + 127) / 128, 512, 0, stream>>>(
            hin, esrc, startn, cnt4, wt + (size_t)l * 81920, pf + l * 128,
            pf + 11008 + bl * 256, pf + 11008 + bl * 256 + 128,
            (l > 0) ? hin : (const __hip_bfloat16*)nullptr, houts[l], (l < 2) ? 1 : 0);
        hin = houts[l];
    }
    pool_kernel<<<GG, 256, 0, stream>>>(houts[2], batch, pooled);
    cls_kernel<<<GG, 64, 0, stream>>>(pooled, pf, flag, (void*)d_out);
}